// Round 5
// baseline (253.509 us; speedup 1.0000x reference)
//
#include <hip/hip_runtime.h>
#include <hip/hip_bf16.h>

// Problem constants (B=4, N=4096, D=1024, H=16, hd=64, G=512, sigma=3)
#define NPOS 4096
#define DIM  1024
#define GSZ  512

#define GAS __attribute__((address_space(1)))
#define LAS __attribute__((address_space(3)))

typedef __attribute__((ext_vector_type(8))) short bf16x8;   // 8 bf16 (4 VGPRs)
typedef __attribute__((ext_vector_type(4))) float f32x4;

__device__ __forceinline__ void async_load16(const void* g, void* l) {
  __builtin_amdgcn_global_load_lds((const GAS void*)g, (LAS void*)l, 16, 0, 0);
}

// Bit-exact replica of np: (arange(N,f32)/4095)*511 then trunc-to-int32.
__device__ __forceinline__ int fidx_of(int n) {
  return (int)(((float)n / 4095.0f) * 511.0f);
}

__device__ __forceinline__ float bf2f(unsigned short s) {
  union { unsigned u; float f; } v; v.u = ((unsigned)s) << 16; return v.f;
}

// exact first row of bin g under fidx_of (g in [0,512]; g>=512 -> 4096)
__device__ __forceinline__ int bin_start(int g) {
  if (g >= GSZ) return NPOS;
  int i0 = (g * 4095 + 510) / 511;
  while (i0 > 0 && fidx_of(i0 - 1) >= g) --i0;
  while (i0 < NPOS && fidx_of(i0) < g) ++i0;
  return i0;
}

// exact [i0,i1) row-range of bin g under fidx_of
// NOTE: bins are 8 or 9 rows EXCEPT bin 511 which has exactly 1 row (n=4095).
__device__ __forceinline__ void bin_range(int g, int& i0, int& i1) {
  i0 = bin_start(g);
  i1 = bin_start(g + 1);
}

// ---------------- all f32->bf16 casts in one launch (r4: 8 floats/thread) ----------------
// blocks [0,8192): x ; [8192,8704): k_w ; [8704,9216): v_w ; [9216,9728): out_w
__global__ __launch_bounds__(256) void cast_all(
    const float* __restrict__ x, const float* __restrict__ kw,
    const float* __restrict__ vw, const float* __restrict__ ow,
    __hip_bfloat16* __restrict__ xb, __hip_bfloat16* __restrict__ kvwb,
    __hip_bfloat16* __restrict__ outwb) {
  int blk = blockIdx.x;
  const float* src; __hip_bfloat16* dst; int off;
  if (blk < 8192)      { src = x;  dst = xb;              off = blk; }
  else if (blk < 8704) { src = kw; dst = kvwb;            off = blk - 8192; }
  else if (blk < 9216) { src = vw; dst = kvwb + 1048576;  off = blk - 8704; }
  else                 { src = ow; dst = outwb;           off = blk - 9216; }
  int i = (off * 256 + threadIdx.x) * 8;
  float4 f0 = *(const float4*)(src + i);
  float4 f1 = *(const float4*)(src + i + 4);
  ushort4 o0, o1;
  __hip_bfloat16 t;
  t = __float2bfloat16(f0.x); o0.x = *(unsigned short*)&t;
  t = __float2bfloat16(f0.y); o0.y = *(unsigned short*)&t;
  t = __float2bfloat16(f0.z); o0.z = *(unsigned short*)&t;
  t = __float2bfloat16(f0.w); o0.w = *(unsigned short*)&t;
  t = __float2bfloat16(f1.x); o1.x = *(unsigned short*)&t;
  t = __float2bfloat16(f1.y); o1.y = *(unsigned short*)&t;
  t = __float2bfloat16(f1.z); o1.z = *(unsigned short*)&t;
  t = __float2bfloat16(f1.w); o1.w = *(unsigned short*)&t;
  *(ushort4*)(dst + i) = o0;
  *(ushort4*)(dst + i + 4) = o1;
}

// ================= 256x256-tile 8-phase bf16 MFMA GEMM (T2+T3+T4+T5) =================
// A: 16384 x 1024 (xb).  B: 2048 x 1024 row-major = [k_w ; v_w].
// 512 threads = 8 waves (2M x 4N), per-wave 128x64 output, BK=64, K=1024 -> 16 K-tiles.
// LDS: 2 dbuf x (A 32KB + B 32KB) = 128 KiB, 1 block/CU, 2 waves/SIMD.
// r3: staging spread across phases; chunk-deadness proofs in DO_TILE comments.
// r5: XCD remap REVERTED to r3 N-panel form. r4's M-panel map dropped FETCH
//     135->49 MB but cost +18 µs: per-XCD concurrent working set (4MB A + 2MB B)
//     thrashed the 4MB L2; at 2 waves/SIMD there is no TLP to hide the misses.
//     HBM fetch is not this kernel's constraint -- keep B-panel L2-resident.

#define BAR()   __builtin_amdgcn_s_barrier()
#define LGKM0() do { asm volatile("s_waitcnt lgkmcnt(0)" ::: "memory"); \
                     __builtin_amdgcn_sched_barrier(0); } while (0)
#define VMW(N)  asm volatile("s_waitcnt vmcnt(" #N ")" ::: "memory")

#define STAGE_A(BUF, KT, C) \
  async_load16(ag0 + (size_t)(KT) * 64 + (size_t)(C) * 65536, &As[BUF][(C) * 4096 + ldst])
#define STAGE_B(BUF, KT, C) \
  async_load16(bg0 + (size_t)(KT) * 64 + (size_t)(C) * 65536, &Bs[BUF][(C) * 4096 + ldst])

#define STAGE_FULL(BUF, KT) do { \
    _Pragma("unroll") \
    for (int c_ = 0; c_ < 4; ++c_) { \
      STAGE_A(BUF, KT, c_); \
      STAGE_B(BUF, KT, c_); \
    } \
  } while (0)

#define LDA(BUF, MT, CB) (*(const bf16x8*)&As[BUF][abase + (MT) * 1024 + (CB)])
#define LDB(BUF, NT, CB) (*(const bf16x8*)&Bs[BUF][bbase + (NT) * 1024 + (CB)])

#define MFMA_Q(MQ, NQ, BF) do { \
    __builtin_amdgcn_s_setprio(1); \
    _Pragma("unroll") \
    for (int m_ = 0; m_ < 4; ++m_) { \
      _Pragma("unroll") \
      for (int n_ = 0; n_ < 2; ++n_) { \
        acc[(MQ)*4+m_][(NQ)*2+n_] = __builtin_amdgcn_mfma_f32_16x16x32_bf16( \
            af[m_][0], BF[n_][0], acc[(MQ)*4+m_][(NQ)*2+n_], 0, 0, 0); \
        acc[(MQ)*4+m_][(NQ)*2+n_] = __builtin_amdgcn_mfma_f32_16x16x32_bf16( \
            af[m_][1], BF[n_][1], acc[(MQ)*4+m_][(NQ)*2+n_], 0, 0, 0); \
      } \
    } \
    __builtin_amdgcn_s_setprio(0); \
  } while (0)

#define DO_TILE(BUF, KT) do { \
    const bool pf_ = (KT) + 2 < 16; \
    /* P1: A-low (8 ds: chunks 0,2) + B-low (4 ds) -> MFMA (0,0) */ \
    _Pragma("unroll") \
    for (int m_ = 0; m_ < 4; ++m_) { af[m_][0] = LDA(BUF, m_, cb0); af[m_][1] = LDA(BUF, m_, cb1); } \
    _Pragma("unroll") \
    for (int n_ = 0; n_ < 2; ++n_) { b0f[n_][0] = LDB(BUF, n_, cb0); b0f[n_][1] = LDB(BUF, n_, cb1); } \
    BAR(); LGKM0(); \
    MFMA_Q(0, 0, b0f); \
    BAR(); \
    /* P2: B-high (4 ds); stage A chunks 0,2 (dead since P1 end-bar) -> MFMA (0,1) */ \
    _Pragma("unroll") \
    for (int n_ = 0; n_ < 2; ++n_) { b1f[n_][0] = LDB(BUF, 2 + n_, cb0); b1f[n_][1] = LDB(BUF, 2 + n_, cb1); } \
    if (pf_) { STAGE_A(BUF, (KT) + 2, 0); STAGE_A(BUF, (KT) + 2, 2); } \
    BAR(); LGKM0(); \
    MFMA_Q(0, 1, b1f); \
    BAR(); \
    /* P3: A-high (8 ds: chunks 1,3); stage B 0..3 (all B reads done) -> MFMA (1,1) */ \
    _Pragma("unroll") \
    for (int m_ = 0; m_ < 4; ++m_) { af[m_][0] = LDA(BUF, 4 + m_, cb0); af[m_][1] = LDA(BUF, 4 + m_, cb1); } \
    if (pf_) { STAGE_B(BUF, (KT) + 2, 0); STAGE_B(BUF, (KT) + 2, 1); \
               STAGE_B(BUF, (KT) + 2, 2); STAGE_B(BUF, (KT) + 2, 3); } \
    BAR(); LGKM0(); \
    MFMA_Q(1, 1, b1f); \
    BAR(); \
    /* P4: stage A chunks 1,3 (dead since P3 end-bar); MFMA (1,0); counted vmcnt */ \
    if (pf_) { STAGE_A(BUF, (KT) + 2, 1); STAGE_A(BUF, (KT) + 2, 3); } \
    MFMA_Q(1, 0, b0f); \
    if (pf_) { VMW(8); } else if ((KT) == 14) { VMW(0); } \
    BAR(); \
  } while (0)

__global__ __launch_bounds__(512, 2) void gemm_kv(
    const __hip_bfloat16* __restrict__ A,
    const __hip_bfloat16* __restrict__ B,
    const float* __restrict__ k_b, const float* __restrict__ v_b,
    __hip_bfloat16* __restrict__ Vb, float* __restrict__ knorm) {
  __shared__ __align__(16) __hip_bfloat16 As[2][16384];   // 2 x 32 KB
  __shared__ __align__(16) __hip_bfloat16 Bs[2][16384];   // 2 x 32 KB
  const int tid = threadIdx.x;

  // XCD-aware bijective remap (nwg=512, 8 XCDs), r3 form: XCD x runs by=x
  // (one 512 KB B-panel, L2-resident) and streams A panels (L3 serves the
  // cross-XCD A reuse). Verified 81 µs; r4's M-panel variant regressed.
  const int l  = blockIdx.y * 64 + blockIdx.x;
  const int vv = (l & 7) * 64 + (l >> 3);
  const int bx = vv & 63, by = vv >> 6;
  const int bm = bx * 256;

  // ---- staging constants: linear LDS dest, pre-swizzled global source (rule #21) ----
  // LDS linear byte L = (c*512+t)*16 -> row r = c*64 + (t>>3); within-row byte (t&7)*16;
  // source col-byte = ((t&7)*16) ^ ((r&7)<<4); involution matched by the ds_read XOR.
  const int sb  = ((((tid & 7) * 16) ^ (((tid >> 3) & 7) << 4)) >> 1);
  const int r0  = tid >> 3;
  const __hip_bfloat16* ag0 = A + (size_t)(bm + r0) * 1024 + sb;
  const __hip_bfloat16* bg0 = B + (size_t)(by * 256 + r0) * 1024 + sb;
  const int ldst = tid * 8;          // element offset of chunk c=0 (chunk adds 4096)

  // ---- fragment addressing ----
  const int wave = tid >> 6, lane = tid & 63;
  const int wr = wave >> 2, wc = wave & 3;        // 2M x 4N waves
  const int m16 = lane & 15, quad = lane >> 4;
  const int swz  = (m16 & 7) << 4;                // byte XOR (row&7)<<4
  const int cb0  = ((quad * 16)      ^ swz) >> 1; // kh=0 element offset in 64-col row
  const int cb1  = ((quad * 16 + 64) ^ swz) >> 1; // kh=1
  const int abase = wr * 8192 + m16 * 64;         // (wr*128 + m16) * 64
  const int bbase = wc * 4096 + m16 * 64;         // (wc*64  + m16) * 64

  f32x4 acc[8][4];
#pragma unroll
  for (int i = 0; i < 8; i++)
#pragma unroll
    for (int j2 = 0; j2 < 4; j2++) acc[i][j2] = (f32x4)0.f;

  bf16x8 af[4][2], b0f[2][2], b1f[2][2];

  // prologue: stage tiles 0 and 1, wait the first (8 of tile1 stay in flight)
  STAGE_FULL(0, 0);
  STAGE_FULL(1, 1);
  VMW(8);
  BAR();

  for (int kt = 0; kt < 16; kt += 2) {
    DO_TILE(0, kt);
    DO_TILE(1, kt + 1);
  }

  // ---- epilogue (identical math to r1..r4) ----
  if (by < 4) {
    // K block: reduce ||k||^2 per (row, head) in-register; head = 64-col span of wave
    const int head = by * 4 + wc;
    float bv[4];
#pragma unroll
    for (int nt = 0; nt < 4; nt++) bv[nt] = k_b[by * 256 + wc * 64 + nt * 16 + m16];
#pragma unroll
    for (int mt = 0; mt < 8; mt++) {
#pragma unroll
      for (int r = 0; r < 4; r++) {
        float s = 0.f;
#pragma unroll
        for (int nt = 0; nt < 4; nt++) {
          float t = acc[mt][nt][r] + bv[nt];
          s += t * t;
        }
        s += __shfl_xor(s, 1);
        s += __shfl_xor(s, 2);
        s += __shfl_xor(s, 4);
        s += __shfl_xor(s, 8);
        if (m16 == 0) {
          int row = bm + wr * 128 + mt * 16 + quad * 4 + r;
          knorm[(size_t)row * 16 + head] = sqrtf(s);
        }
      }
    }
  } else {
    // V block: bf16 store into Vb (row stride 1024)
    const int colb = (by - 4) * 256 + wc * 64;
#pragma unroll
    for (int mt = 0; mt < 8; mt++) {
#pragma unroll
      for (int nt = 0; nt < 4; nt++) {
        int col = colb + nt * 16 + m16;
        float bvv = v_b[col];
#pragma unroll
        for (int r = 0; r < 4; r++) {
          int row = bm + wr * 128 + mt * 16 + quad * 4 + r;
          Vb[(size_t)row * 1024 + col] = __float2bfloat16(acc[mt][nt][r] + bvv);
        }
      }
    }
  }
}

// ---------------- output GEMM fused with gather (r5: 128x128 BK=64 + streamer) ----------------
// A = convb: 2048 x 1024 bf16 (rows = b*512+g). B = outwb: 1024 x 1024 bf16.
// Grid (16,8) = 128 blocks, 256 threads, r0-proven gemm_bt K-loop (BK=64 as two
// 32-halves, one barrier pair per 32 MFMAs). Epilogue: stage 128x128 f32 tile
// (+bias) into padded LDS (stride 132), then stream the CONTIGUOUS duplicated
// output-row range [bin_start(g0), bin_start(g0+128)) with coalesced float4
// stores, zero divergence. Values bit-identical to the outc+gather path.
__global__ __launch_bounds__(256) void gemm_outc(
    const __hip_bfloat16* __restrict__ A,
    const __hip_bfloat16* __restrict__ B,
    const float* __restrict__ bias,
    float* __restrict__ C) {
  const int K = 1024;
  __shared__ __align__(16) __hip_bfloat16 Aso[2][128 * 32];  // 16 KB
  __shared__ __align__(16) __hip_bfloat16 Bso[2][128 * 32];  // 16 KB
  __shared__ __align__(16) float ctile[128 * 132];           // 66 KB, bank-skewed
  const int tid = threadIdx.x;
  const int bm = blockIdx.x * 128, bn = blockIdx.y * 128;

  const int srow = tid >> 2;          // 0..63
  const int scol = (tid & 3) * 8;     // 0,8,16,24
  const __hip_bfloat16* ap0 = A + (size_t)(bm + srow) * K + scol;
  const __hip_bfloat16* ap1 = A + (size_t)(bm + srow + 64) * K + scol;
  const __hip_bfloat16* bp0 = B + (size_t)(bn + srow) * K + scol;
  const __hip_bfloat16* bp1 = B + (size_t)(bn + srow + 64) * K + scol;
  const int soff = srow * 32 + scol;  // lane-ordered: tid*16B within each half

  const int wave = tid >> 6, lane = tid & 63;
  const int wm = (wave >> 1) * 64, wn = (wave & 1) * 64;
  const int m16 = lane & 15, quad = lane >> 4;

  f32x4 acc[4][4];
#pragma unroll
  for (int i = 0; i < 4; i++)
#pragma unroll
    for (int j = 0; j < 4; j++) acc[i][j] = (f32x4)0.f;

  for (int k0 = 0; k0 < K; k0 += 64) {
    async_load16(ap0 + k0, &Aso[0][soff]);
    async_load16(ap1 + k0, &Aso[0][soff + 64 * 32]);
    async_load16(bp0 + k0, &Bso[0][soff]);
    async_load16(bp1 + k0, &Bso[0][soff + 64 * 32]);
    async_load16(ap0 + k0 + 32, &Aso[1][soff]);
    async_load16(ap1 + k0 + 32, &Aso[1][soff + 64 * 32]);
    async_load16(bp0 + k0 + 32, &Bso[1][soff]);
    async_load16(bp1 + k0 + 32, &Bso[1][soff + 64 * 32]);
    __syncthreads();
#pragma unroll
    for (int h = 0; h < 2; h++) {
      bf16x8 af[4], bfr[4];
#pragma unroll
      for (int mt = 0; mt < 4; mt++)
        af[mt] = *(const bf16x8*)&Aso[h][(wm + mt * 16 + m16) * 32 + quad * 8];
#pragma unroll
      for (int nt = 0; nt < 4; nt++)
        bfr[nt] = *(const bf16x8*)&Bso[h][(wn + nt * 16 + m16) * 32 + quad * 8];
#pragma unroll
      for (int mt = 0; mt < 4; mt++)
#pragma unroll
        for (int nt = 0; nt < 4; nt++)
          acc[mt][nt] = __builtin_amdgcn_mfma_f32_16x16x32_bf16(af[mt], bfr[nt], acc[mt][nt], 0, 0, 0);
    }
    __syncthreads();
  }

  // stage tile (+bias) into padded LDS
#pragma unroll
  for (int mt = 0; mt < 4; mt++) {
#pragma unroll
    for (int nt = 0; nt < 4; nt++) {
      int lcol = wn + nt * 16 + m16;
      float bv = bias[bn + lcol];
#pragma unroll
      for (int r = 0; r < 4; r++) {
        int lrow = wm + mt * 16 + quad * 4 + r;
        ctile[lrow * 132 + lcol] = acc[mt][nt][r] + bv;
      }
    }
  }
  __syncthreads();

  // stream duplicated rows: tile covers g in [g0, g0+128) of batch b
  // (tiles never straddle the 512-row batch boundary since 128 | 512).
  const int b  = bm >> 9;
  const int g0 = bm & (GSZ - 1);
  const int n0 = bin_start(g0);
  const int n1 = bin_start(g0 + 128);     // g0+128 == 512 -> 4096
  const int total = (n1 - n0) * 32;       // 32 float4-chunks per 128-col row slice
  float* obase = C + (((size_t)b << 12)) * DIM + bn;
  for (int idx = tid; idx < total; idx += 256) {
    int n  = n0 + (idx >> 5);
    int c4 = (idx & 31) * 4;
    int lg = fidx_of(n) - g0;
    float4 v = *(const float4*)&ctile[lg * 132 + c4];
    *(float4*)(obase + (size_t)n * DIM + c4) = v;
  }
}

// ---------------- field: segment-sum of v * ||k|| into G bins ----------------
// knorm-fused variant: phase 1 is a 144-load f32 gather of precomputed norms.
__global__ __launch_bounds__(256) void wv_field_kernel(
    const __hip_bfloat16* __restrict__ V, const float* __restrict__ knorm,
    float* __restrict__ field) {
  const int b = blockIdx.x, g = blockIdx.y;
  int i0, i1;
  bin_range(g, i0, i1);
  int cnt = i1 - i0;                 // 1, 8 or 9
  if (cnt > 9) cnt = 9;
  __shared__ float km[9][16];        // [row][head]
  const int tid = threadIdx.x;
  if (tid < 144) {                   // phase 1: fetch ||k|| per (row, head); zero-fill r>=cnt
    int r = tid >> 4, h = tid & 15;
    km[r][h] = (r < cnt) ? knorm[(size_t)(b * NPOS + i0 + r) * 16 + h] : 0.f;
  }
  __syncthreads();
  const int c0 = tid * 4, h = tid >> 4;   // h = c0>>6
  const unsigned short* vbase = (const unsigned short*)V + (size_t)(b * NPOS + i0) * 1024 + c0;
  ushort4 vv[8];
  float ww[8];
#pragma unroll
  for (int j = 0; j < 8; ++j) {
    int jc = (j < cnt) ? j : 0;           // clamp: valid row, weight 0 below
    vv[j] = *(const ushort4*)(vbase + (size_t)jc * 1024);
    ww[j] = (j < cnt) ? km[j][h] : 0.f;
  }
  float a0 = 0.f, a1 = 0.f, a2 = 0.f, a3 = 0.f;
#pragma unroll
  for (int j = 0; j < 8; ++j) {
    a0 += ww[j] * bf2f(vv[j].x); a1 += ww[j] * bf2f(vv[j].y);
    a2 += ww[j] * bf2f(vv[j].z); a3 += ww[j] * bf2f(vv[j].w);
  }
  if (cnt == 9) {
    ushort4 v8 = *(const ushort4*)(vbase + (size_t)8 * 1024);
    float w8 = km[8][h];
    a0 += w8 * bf2f(v8.x); a1 += w8 * bf2f(v8.y);
    a2 += w8 * bf2f(v8.z); a3 += w8 * bf2f(v8.w);
  }
  *(float4*)(field + ((size_t)(b * GSZ + g)) * DIM + c0) = make_float4(a0, a1, a2, a3);
}

// ---------------- causal conv as EMA recurrence, LDS-staged (r9, FROZEN) ----------------
__global__ __launch_bounds__(256) void conv_ema_kernel(
    const float* __restrict__ field, __hip_bfloat16* __restrict__ convb) {
  const int b = blockIdx.x, h = blockIdx.y, n0 = blockIdx.z * 64;
  __shared__ float slab[128 * 64];
  const int tid = threadIdx.x;
  const float* fb = field + (size_t)b * GSZ * DIM + h * 64;
  for (int i = tid; i < 128 * 16; i += 256) {         // float4 loads, 8/thread
    int row = i >> 4, c4 = i & 15;
    int gg = (n0 + 257 + row) & (GSZ - 1);
    *(float4*)&slab[row * 64 + c4 * 4] = *(const float4*)(fb + (size_t)gg * DIM + c4 * 4);
  }
  __syncthreads();
  const float a = 0.71653131057378927f;   // exp(-1/3)
  const float w1 = 1.0f - a;
  const int c = tid & 63, sub = tid >> 6;
  const int e0 = sub * 16;                // emit slab range [e0, e0+16)
  float acc = 0.f;
#pragma unroll 4
  for (int t = e0 + 79; t >= e0 + 16; --t)            // 64-step warm-up (a^64 ~ 5e-10)
    acc = w1 * slab[t * 64 + c] + a * acc;
#pragma unroll
  for (int t = e0 + 15; t >= e0; --t) {
    acc = w1 * slab[t * 64 + c] + a * acc;
    convb[((size_t)(b * GSZ) + n0 + t) * DIM + h * 64 + c] = __float2bfloat16(acc);
  }
}

extern "C" void kernel_launch(void* const* d_in, const int* in_sizes, int n_in,
                              void* d_out, int out_size, void* d_ws, size_t ws_size,
                              hipStream_t stream) {
  (void)in_sizes; (void)n_in; (void)out_size; (void)ws_size;
  const float* x     = (const float*)d_in[0];
  // d_in[1]=q_w, d_in[2]=q_b: dead in the reference — skipped.
  const float* k_w   = (const float*)d_in[3];
  const float* k_b   = (const float*)d_in[4];
  const float* v_w   = (const float*)d_in[5];
  const float* v_b   = (const float*)d_in[6];
  const float* out_w = (const float*)d_in[7];
  const float* out_b = (const float*)d_in[8];

  char* p = (char*)d_ws;
  __hip_bfloat16* xb    = (__hip_bfloat16*)p;         p += (size_t)16384 * 1024 * 2;  // 32 MB (dead after gemm_kv)
  __hip_bfloat16* kvwb  = (__hip_bfloat16*)p; p += (size_t)2048 * 1024 * 2;   // 4 MB
  __hip_bfloat16* outwb = (__hip_bfloat16*)p; p += (size_t)1024 * 1024 * 2;   // 2 MB
  __hip_bfloat16* Vb    = (__hip_bfloat16*)p; p += (size_t)16384 * 1024 * 2;  // 32 MB (V only; K never materialized)
  float*          knorm = (float*)p;          p += (size_t)16384 * 16 * 4;    // 1 MB
  float*          field = (float*)p;          p += (size_t)4 * 512 * 1024 * 4;// 8 MB
  __hip_bfloat16* convb = (__hip_bfloat16*)p;                                 // 4 MB

  cast_all<<<9728, 256, 0, stream>>>(x, k_w, v_w, out_w, xb, kvwb, outwb);

  // fused K+V projection (256^2 8-phase): K-half -> knorm in-epilogue; V-half -> Vb
  gemm_kv<<<dim3(64, 8), 512, 0, stream>>>(xb, kvwb, k_b, v_b, Vb, knorm);

  wv_field_kernel<<<dim3(4, 512), 256, 0, stream>>>(Vb, knorm, field);
  conv_ema_kernel<<<dim3(4, 16, 8), 256, 0, stream>>>(field, convb);

  // output GEMM with fused bin-duplication (128x128 BK=64 + LDS streamer, writes d_out)
  gemm_outc<<<dim3(16, 8), 256, 0, stream>>>(convb, outwb, out_b, (float*)d_out);
}

// Round 6
// 244.970 us; speedup vs baseline: 1.0349x; 1.0349x over previous
//
#include <hip/hip_runtime.h>
#include <hip/hip_bf16.h>

// Problem constants (B=4, N=4096, D=1024, H=16, hd=64, G=512, sigma=3)
#define NPOS 4096
#define DIM  1024
#define GSZ  512

#define GAS __attribute__((address_space(1)))
#define LAS __attribute__((address_space(3)))

typedef __attribute__((ext_vector_type(8))) short bf16x8;   // 8 bf16 (4 VGPRs)
typedef __attribute__((ext_vector_type(4))) float f32x4;

__device__ __forceinline__ void async_load16(const void* g, void* l) {
  __builtin_amdgcn_global_load_lds((const GAS void*)g, (LAS void*)l, 16, 0, 0);
}

// Bit-exact replica of np: (arange(N,f32)/4095)*511 then trunc-to-int32.
__device__ __forceinline__ int fidx_of(int n) {
  return (int)(((float)n / 4095.0f) * 511.0f);
}

__device__ __forceinline__ float bf2f(unsigned short s) {
  union { unsigned u; float f; } v; v.u = ((unsigned)s) << 16; return v.f;
}

// exact first row of bin g under fidx_of (g in [0,512]; g>=512 -> 4096)
__device__ __forceinline__ int bin_start(int g) {
  if (g >= GSZ) return NPOS;
  int i0 = (g * 4095 + 510) / 511;
  while (i0 > 0 && fidx_of(i0 - 1) >= g) --i0;
  while (i0 < NPOS && fidx_of(i0) < g) ++i0;
  return i0;
}

// exact [i0,i1) row-range of bin g under fidx_of
// NOTE: bins are 8 or 9 rows EXCEPT bin 511 which has exactly 1 row (n=4095).
__device__ __forceinline__ void bin_range(int g, int& i0, int& i1) {
  i0 = bin_start(g);
  i1 = bin_start(g + 1);
}

// ---------------- all f32->bf16 casts in one launch (r4: 8 floats/thread) ----------------
// blocks [0,8192): x ; [8192,8704): k_w ; [8704,9216): v_w ; [9216,9728): out_w
__global__ __launch_bounds__(256) void cast_all(
    const float* __restrict__ x, const float* __restrict__ kw,
    const float* __restrict__ vw, const float* __restrict__ ow,
    __hip_bfloat16* __restrict__ xb, __hip_bfloat16* __restrict__ kvwb,
    __hip_bfloat16* __restrict__ outwb) {
  int blk = blockIdx.x;
  const float* src; __hip_bfloat16* dst; int off;
  if (blk < 8192)      { src = x;  dst = xb;              off = blk; }
  else if (blk < 8704) { src = kw; dst = kvwb;            off = blk - 8192; }
  else if (blk < 9216) { src = vw; dst = kvwb + 1048576;  off = blk - 8704; }
  else                 { src = ow; dst = outwb;           off = blk - 9216; }
  int i = (off * 256 + threadIdx.x) * 8;
  float4 f0 = *(const float4*)(src + i);
  float4 f1 = *(const float4*)(src + i + 4);
  ushort4 o0, o1;
  __hip_bfloat16 t;
  t = __float2bfloat16(f0.x); o0.x = *(unsigned short*)&t;
  t = __float2bfloat16(f0.y); o0.y = *(unsigned short*)&t;
  t = __float2bfloat16(f0.z); o0.z = *(unsigned short*)&t;
  t = __float2bfloat16(f0.w); o0.w = *(unsigned short*)&t;
  t = __float2bfloat16(f1.x); o1.x = *(unsigned short*)&t;
  t = __float2bfloat16(f1.y); o1.y = *(unsigned short*)&t;
  t = __float2bfloat16(f1.z); o1.z = *(unsigned short*)&t;
  t = __float2bfloat16(f1.w); o1.w = *(unsigned short*)&t;
  *(ushort4*)(dst + i) = o0;
  *(ushort4*)(dst + i + 4) = o1;
}

// ================= 256x256-tile 8-phase bf16 MFMA GEMM (T2+T3+T4+T5) =================
// A: 16384 x 1024 (xb).  B: 2048 x 1024 row-major = [k_w ; v_w].
// 512 threads = 8 waves (2M x 4N), per-wave 128x64 output, BK=64, K=1024 -> 16 K-tiles.
// LDS: 2 dbuf x (A 32KB + B 32KB) = 128 KiB, 1 block/CU, 2 waves/SIMD.
// r3: staging spread across phases; chunk-deadness proofs in DO_TILE comments.
// r5: XCD remap r3 N-panel form FROZEN at ~80 µs (r4's M-panel map: FETCH
//     135->49 MB but +18 µs -- 6 MB concurrent working set thrashed the 4 MB L2).

#define BAR()   __builtin_amdgcn_s_barrier()
#define LGKM0() do { asm volatile("s_waitcnt lgkmcnt(0)" ::: "memory"); \
                     __builtin_amdgcn_sched_barrier(0); } while (0)
#define VMW(N)  asm volatile("s_waitcnt vmcnt(" #N ")" ::: "memory")

#define STAGE_A(BUF, KT, C) \
  async_load16(ag0 + (size_t)(KT) * 64 + (size_t)(C) * 65536, &As[BUF][(C) * 4096 + ldst])
#define STAGE_B(BUF, KT, C) \
  async_load16(bg0 + (size_t)(KT) * 64 + (size_t)(C) * 65536, &Bs[BUF][(C) * 4096 + ldst])

#define STAGE_FULL(BUF, KT) do { \
    _Pragma("unroll") \
    for (int c_ = 0; c_ < 4; ++c_) { \
      STAGE_A(BUF, KT, c_); \
      STAGE_B(BUF, KT, c_); \
    } \
  } while (0)

#define LDA(BUF, MT, CB) (*(const bf16x8*)&As[BUF][abase + (MT) * 1024 + (CB)])
#define LDB(BUF, NT, CB) (*(const bf16x8*)&Bs[BUF][bbase + (NT) * 1024 + (CB)])

#define MFMA_Q(MQ, NQ, BF) do { \
    __builtin_amdgcn_s_setprio(1); \
    _Pragma("unroll") \
    for (int m_ = 0; m_ < 4; ++m_) { \
      _Pragma("unroll") \
      for (int n_ = 0; n_ < 2; ++n_) { \
        acc[(MQ)*4+m_][(NQ)*2+n_] = __builtin_amdgcn_mfma_f32_16x16x32_bf16( \
            af[m_][0], BF[n_][0], acc[(MQ)*4+m_][(NQ)*2+n_], 0, 0, 0); \
        acc[(MQ)*4+m_][(NQ)*2+n_] = __builtin_amdgcn_mfma_f32_16x16x32_bf16( \
            af[m_][1], BF[n_][1], acc[(MQ)*4+m_][(NQ)*2+n_], 0, 0, 0); \
      } \
    } \
    __builtin_amdgcn_s_setprio(0); \
  } while (0)

#define DO_TILE(BUF, KT) do { \
    const bool pf_ = (KT) + 2 < 16; \
    /* P1: A-low (8 ds: chunks 0,2) + B-low (4 ds) -> MFMA (0,0) */ \
    _Pragma("unroll") \
    for (int m_ = 0; m_ < 4; ++m_) { af[m_][0] = LDA(BUF, m_, cb0); af[m_][1] = LDA(BUF, m_, cb1); } \
    _Pragma("unroll") \
    for (int n_ = 0; n_ < 2; ++n_) { b0f[n_][0] = LDB(BUF, n_, cb0); b0f[n_][1] = LDB(BUF, n_, cb1); } \
    BAR(); LGKM0(); \
    MFMA_Q(0, 0, b0f); \
    BAR(); \
    /* P2: B-high (4 ds); stage A chunks 0,2 (dead since P1 end-bar) -> MFMA (0,1) */ \
    _Pragma("unroll") \
    for (int n_ = 0; n_ < 2; ++n_) { b1f[n_][0] = LDB(BUF, 2 + n_, cb0); b1f[n_][1] = LDB(BUF, 2 + n_, cb1); } \
    if (pf_) { STAGE_A(BUF, (KT) + 2, 0); STAGE_A(BUF, (KT) + 2, 2); } \
    BAR(); LGKM0(); \
    MFMA_Q(0, 1, b1f); \
    BAR(); \
    /* P3: A-high (8 ds: chunks 1,3); stage B 0..3 (all B reads done) -> MFMA (1,1) */ \
    _Pragma("unroll") \
    for (int m_ = 0; m_ < 4; ++m_) { af[m_][0] = LDA(BUF, 4 + m_, cb0); af[m_][1] = LDA(BUF, 4 + m_, cb1); } \
    if (pf_) { STAGE_B(BUF, (KT) + 2, 0); STAGE_B(BUF, (KT) + 2, 1); \
               STAGE_B(BUF, (KT) + 2, 2); STAGE_B(BUF, (KT) + 2, 3); } \
    BAR(); LGKM0(); \
    MFMA_Q(1, 1, b1f); \
    BAR(); \
    /* P4: stage A chunks 1,3 (dead since P3 end-bar); MFMA (1,0); counted vmcnt */ \
    if (pf_) { STAGE_A(BUF, (KT) + 2, 1); STAGE_A(BUF, (KT) + 2, 3); } \
    MFMA_Q(1, 0, b0f); \
    if (pf_) { VMW(8); } else if ((KT) == 14) { VMW(0); } \
    BAR(); \
  } while (0)

__global__ __launch_bounds__(512, 2) void gemm_kv(
    const __hip_bfloat16* __restrict__ A,
    const __hip_bfloat16* __restrict__ B,
    const float* __restrict__ k_b, const float* __restrict__ v_b,
    __hip_bfloat16* __restrict__ Vb, float* __restrict__ knorm) {
  __shared__ __align__(16) __hip_bfloat16 As[2][16384];   // 2 x 32 KB
  __shared__ __align__(16) __hip_bfloat16 Bs[2][16384];   // 2 x 32 KB
  const int tid = threadIdx.x;

  // XCD-aware bijective remap (nwg=512, 8 XCDs), r3 form: XCD x runs by=x
  // (one 512 KB B-panel, L2-resident) and streams A panels. FROZEN (~80 µs).
  const int l  = blockIdx.y * 64 + blockIdx.x;
  const int vv = (l & 7) * 64 + (l >> 3);
  const int bx = vv & 63, by = vv >> 6;
  const int bm = bx * 256;

  // ---- staging constants: linear LDS dest, pre-swizzled global source (rule #21) ----
  // LDS linear byte L = (c*512+t)*16 -> row r = c*64 + (t>>3); within-row byte (t&7)*16;
  // source col-byte = ((t&7)*16) ^ ((r&7)<<4); involution matched by the ds_read XOR.
  const int sb  = ((((tid & 7) * 16) ^ (((tid >> 3) & 7) << 4)) >> 1);
  const int r0  = tid >> 3;
  const __hip_bfloat16* ag0 = A + (size_t)(bm + r0) * 1024 + sb;
  const __hip_bfloat16* bg0 = B + (size_t)(by * 256 + r0) * 1024 + sb;
  const int ldst = tid * 8;          // element offset of chunk c=0 (chunk adds 4096)

  // ---- fragment addressing ----
  const int wave = tid >> 6, lane = tid & 63;
  const int wr = wave >> 2, wc = wave & 3;        // 2M x 4N waves
  const int m16 = lane & 15, quad = lane >> 4;
  const int swz  = (m16 & 7) << 4;                // byte XOR (row&7)<<4
  const int cb0  = ((quad * 16)      ^ swz) >> 1; // kh=0 element offset in 64-col row
  const int cb1  = ((quad * 16 + 64) ^ swz) >> 1; // kh=1
  const int abase = wr * 8192 + m16 * 64;         // (wr*128 + m16) * 64
  const int bbase = wc * 4096 + m16 * 64;         // (wc*64  + m16) * 64

  f32x4 acc[8][4];
#pragma unroll
  for (int i = 0; i < 8; i++)
#pragma unroll
    for (int j2 = 0; j2 < 4; j2++) acc[i][j2] = (f32x4)0.f;

  bf16x8 af[4][2], b0f[2][2], b1f[2][2];

  // prologue: stage tiles 0 and 1, wait the first (8 of tile1 stay in flight)
  STAGE_FULL(0, 0);
  STAGE_FULL(1, 1);
  VMW(8);
  BAR();

  for (int kt = 0; kt < 16; kt += 2) {
    DO_TILE(0, kt);
    DO_TILE(1, kt + 1);
  }

  // ---- epilogue (identical math to r1..r5) ----
  if (by < 4) {
    // K block: reduce ||k||^2 per (row, head) in-register; head = 64-col span of wave
    const int head = by * 4 + wc;
    float bv[4];
#pragma unroll
    for (int nt = 0; nt < 4; nt++) bv[nt] = k_b[by * 256 + wc * 64 + nt * 16 + m16];
#pragma unroll
    for (int mt = 0; mt < 8; mt++) {
#pragma unroll
      for (int r = 0; r < 4; r++) {
        float s = 0.f;
#pragma unroll
        for (int nt = 0; nt < 4; nt++) {
          float t = acc[mt][nt][r] + bv[nt];
          s += t * t;
        }
        s += __shfl_xor(s, 1);
        s += __shfl_xor(s, 2);
        s += __shfl_xor(s, 4);
        s += __shfl_xor(s, 8);
        if (m16 == 0) {
          int row = bm + wr * 128 + mt * 16 + quad * 4 + r;
          knorm[(size_t)row * 16 + head] = sqrtf(s);
        }
      }
    }
  } else {
    // V block: bf16 store into Vb (row stride 1024)
    const int colb = (by - 4) * 256 + wc * 64;
#pragma unroll
    for (int mt = 0; mt < 8; mt++) {
#pragma unroll
      for (int nt = 0; nt < 4; nt++) {
        int col = colb + nt * 16 + m16;
        float bvv = v_b[col];
#pragma unroll
        for (int r = 0; r < 4; r++) {
          int row = bm + wr * 128 + mt * 16 + quad * 4 + r;
          Vb[(size_t)row * 1024 + col] = __float2bfloat16(acc[mt][nt][r] + bvv);
        }
      }
    }
  }
}

// ---------------- output GEMM fused with gather (r6: r4 64x64 geometry, BK=64) ----------------
// A = convb: 2048 x 1024 bf16 (rows = b*512+g). B = outwb: 1024 x 1024 bf16.
// Grid (32,16) = 512 blocks (2/CU -- r5's 128-block 128^2 variant halved the GPU
// and regressed ~29 µs; 64^2 @ 512 blocks is the proven config). r6 upgrade: BK=64
// staged as two 32-halves per barrier pair (r0 gemm_bt trick) -> 32 barriers, was 64.
// LDS: 2x4KB A + 2x4KB B + 17.4KB ctile = 33.4 KB -> 4 blocks/CU by LDS.
// Epilogue (r4-proven): stage 64x64 f32 tile (+bias) into padded LDS (stride 68),
// then stream the CONTIGUOUS duplicated row range [bin_start(g0), bin_start(g0+64))
// with coalesced float4 stores, zero divergence. Values bit-identical.
__global__ __launch_bounds__(256) void gemm_outc(
    const __hip_bfloat16* __restrict__ A,
    const __hip_bfloat16* __restrict__ B,
    const float* __restrict__ bias,
    float* __restrict__ C) {
  const int K = 1024;
  __shared__ __align__(16) __hip_bfloat16 Aso[2][64 * 32];
  __shared__ __align__(16) __hip_bfloat16 Bso[2][64 * 32];
  __shared__ __align__(16) float ctile[64 * 68];   // stride 68 f32: float4-aligned, bank-skewed
  const int tid = threadIdx.x;
  const int bm = blockIdx.x * 64, bn = blockIdx.y * 64;

  const int srow = tid >> 2;          // 0..63
  const int scol = (tid & 3) * 8;     // 0,8,16,24
  const __hip_bfloat16* ap = A + (size_t)(bm + srow) * K + scol;
  const __hip_bfloat16* bp = B + (size_t)(bn + srow) * K + scol;
  const int soff = srow * 32 + scol;  // lane-ordered: tid*16B within each half

  const int wave = tid >> 6, lane = tid & 63;
  const int wm = (wave >> 1) * 32, wn = (wave & 1) * 32;   // 2x2 waves, 32x32 each
  const int m16 = lane & 15, quad = lane >> 4;

  f32x4 acc[2][2];
#pragma unroll
  for (int i = 0; i < 2; i++)
#pragma unroll
    for (int j = 0; j < 2; j++) acc[i][j] = (f32x4)0.f;

  for (int k0 = 0; k0 < K; k0 += 64) {
    // stage both 32-wide halves, then one barrier pair for 16 MFMAs
    async_load16(ap + k0,      &Aso[0][soff]);
    async_load16(bp + k0,      &Bso[0][soff]);
    async_load16(ap + k0 + 32, &Aso[1][soff]);
    async_load16(bp + k0 + 32, &Bso[1][soff]);
    __syncthreads();
#pragma unroll
    for (int h = 0; h < 2; h++) {
      bf16x8 afr[2], bfr[2];
#pragma unroll
      for (int mt = 0; mt < 2; mt++)
        afr[mt] = *(const bf16x8*)&Aso[h][(wm + mt * 16 + m16) * 32 + quad * 8];
#pragma unroll
      for (int nt = 0; nt < 2; nt++)
        bfr[nt] = *(const bf16x8*)&Bso[h][(wn + nt * 16 + m16) * 32 + quad * 8];
#pragma unroll
      for (int mt = 0; mt < 2; mt++)
#pragma unroll
        for (int nt = 0; nt < 2; nt++)
          acc[mt][nt] = __builtin_amdgcn_mfma_f32_16x16x32_bf16(afr[mt], bfr[nt], acc[mt][nt], 0, 0, 0);
    }
    __syncthreads();
  }

  // stage tile (+bias) into padded LDS
#pragma unroll
  for (int mt = 0; mt < 2; mt++) {
#pragma unroll
    for (int nt = 0; nt < 2; nt++) {
      int lcol = wn + nt * 16 + m16;
      float bv = bias[bn + lcol];
#pragma unroll
      for (int r = 0; r < 4; r++) {
        int lrow = wm + mt * 16 + quad * 4 + r;
        ctile[lrow * 68 + lcol] = acc[mt][nt][r] + bv;
      }
    }
  }
  __syncthreads();

  // stream duplicated rows: tile covers g in [g0, g0+64) of batch b (tiles never
  // straddle the 512-row batch boundary since 64 | 512).
  const int b  = bm >> 9;
  const int g0 = bm & (GSZ - 1);
  const int n0 = bin_start(g0);
  const int n1 = bin_start(g0 + 64);      // g0+64 == 512 -> 4096
  const int total = (n1 - n0) * 16;       // 16 float4-chunks per 64-col row slice
  float* obase = C + (((size_t)b << 12)) * DIM + bn;
  for (int idx = tid; idx < total; idx += 256) {
    int n  = n0 + (idx >> 4);
    int c4 = (idx & 15) * 4;
    int lg = fidx_of(n) - g0;
    float4 v = *(const float4*)&ctile[lg * 68 + c4];
    *(float4*)(obase + (size_t)n * DIM + c4) = v;
  }
}

// ---------------- field: segment-sum of v * ||k|| into G bins ----------------
// knorm-fused variant: phase 1 is a 144-load f32 gather of precomputed norms.
__global__ __launch_bounds__(256) void wv_field_kernel(
    const __hip_bfloat16* __restrict__ V, const float* __restrict__ knorm,
    float* __restrict__ field) {
  const int b = blockIdx.x, g = blockIdx.y;
  int i0, i1;
  bin_range(g, i0, i1);
  int cnt = i1 - i0;                 // 1, 8 or 9
  if (cnt > 9) cnt = 9;
  __shared__ float km[9][16];        // [row][head]
  const int tid = threadIdx.x;
  if (tid < 144) {                   // phase 1: fetch ||k|| per (row, head); zero-fill r>=cnt
    int r = tid >> 4, h = tid & 15;
    km[r][h] = (r < cnt) ? knorm[(size_t)(b * NPOS + i0 + r) * 16 + h] : 0.f;
  }
  __syncthreads();
  const int c0 = tid * 4, h = tid >> 4;   // h = c0>>6
  const unsigned short* vbase = (const unsigned short*)V + (size_t)(b * NPOS + i0) * 1024 + c0;
  ushort4 vv[8];
  float ww[8];
#pragma unroll
  for (int j = 0; j < 8; ++j) {
    int jc = (j < cnt) ? j : 0;           // clamp: valid row, weight 0 below
    vv[j] = *(const ushort4*)(vbase + (size_t)jc * 1024);
    ww[j] = (j < cnt) ? km[j][h] : 0.f;
  }
  float a0 = 0.f, a1 = 0.f, a2 = 0.f, a3 = 0.f;
#pragma unroll
  for (int j = 0; j < 8; ++j) {
    a0 += ww[j] * bf2f(vv[j].x); a1 += ww[j] * bf2f(vv[j].y);
    a2 += ww[j] * bf2f(vv[j].z); a3 += ww[j] * bf2f(vv[j].w);
  }
  if (cnt == 9) {
    ushort4 v8 = *(const ushort4*)(vbase + (size_t)8 * 1024);
    float w8 = km[8][h];
    a0 += w8 * bf2f(v8.x); a1 += w8 * bf2f(v8.y);
    a2 += w8 * bf2f(v8.z); a3 += w8 * bf2f(v8.w);
  }
  *(float4*)(field + ((size_t)(b * GSZ + g)) * DIM + c0) = make_float4(a0, a1, a2, a3);
}

// ---------------- causal conv as EMA recurrence, LDS-staged (r9, FROZEN) ----------------
__global__ __launch_bounds__(256) void conv_ema_kernel(
    const float* __restrict__ field, __hip_bfloat16* __restrict__ convb) {
  const int b = blockIdx.x, h = blockIdx.y, n0 = blockIdx.z * 64;
  __shared__ float slab[128 * 64];
  const int tid = threadIdx.x;
  const float* fb = field + (size_t)b * GSZ * DIM + h * 64;
  for (int i = tid; i < 128 * 16; i += 256) {         // float4 loads, 8/thread
    int row = i >> 4, c4 = i & 15;
    int gg = (n0 + 257 + row) & (GSZ - 1);
    *(float4*)&slab[row * 64 + c4 * 4] = *(const float4*)(fb + (size_t)gg * DIM + c4 * 4);
  }
  __syncthreads();
  const float a = 0.71653131057378927f;   // exp(-1/3)
  const float w1 = 1.0f - a;
  const int c = tid & 63, sub = tid >> 6;
  const int e0 = sub * 16;                // emit slab range [e0, e0+16)
  float acc = 0.f;
#pragma unroll 4
  for (int t = e0 + 79; t >= e0 + 16; --t)            // 64-step warm-up (a^64 ~ 5e-10)
    acc = w1 * slab[t * 64 + c] + a * acc;
#pragma unroll
  for (int t = e0 + 15; t >= e0; --t) {
    acc = w1 * slab[t * 64 + c] + a * acc;
    convb[((size_t)(b * GSZ) + n0 + t) * DIM + h * 64 + c] = __float2bfloat16(acc);
  }
}

extern "C" void kernel_launch(void* const* d_in, const int* in_sizes, int n_in,
                              void* d_out, int out_size, void* d_ws, size_t ws_size,
                              hipStream_t stream) {
  (void)in_sizes; (void)n_in; (void)out_size; (void)ws_size;
  const float* x     = (const float*)d_in[0];
  // d_in[1]=q_w, d_in[2]=q_b: dead in the reference — skipped.
  const float* k_w   = (const float*)d_in[3];
  const float* k_b   = (const float*)d_in[4];
  const float* v_w   = (const float*)d_in[5];
  const float* v_b   = (const float*)d_in[6];
  const float* out_w = (const float*)d_in[7];
  const float* out_b = (const float*)d_in[8];

  char* p = (char*)d_ws;
  __hip_bfloat16* xb    = (__hip_bfloat16*)p;         p += (size_t)16384 * 1024 * 2;  // 32 MB (dead after gemm_kv)
  __hip_bfloat16* kvwb  = (__hip_bfloat16*)p; p += (size_t)2048 * 1024 * 2;   // 4 MB
  __hip_bfloat16* outwb = (__hip_bfloat16*)p; p += (size_t)1024 * 1024 * 2;   // 2 MB
  __hip_bfloat16* Vb    = (__hip_bfloat16*)p; p += (size_t)16384 * 1024 * 2;  // 32 MB (V only; K never materialized)
  float*          knorm = (float*)p;          p += (size_t)16384 * 16 * 4;    // 1 MB
  float*          field = (float*)p;          p += (size_t)4 * 512 * 1024 * 4;// 8 MB
  __hip_bfloat16* convb = (__hip_bfloat16*)p;                                 // 4 MB

  cast_all<<<9728, 256, 0, stream>>>(x, k_w, v_w, out_w, xb, kvwb, outwb);

  // fused K+V projection (256^2 8-phase): K-half -> knorm in-epilogue; V-half -> Vb
  gemm_kv<<<dim3(64, 8), 512, 0, stream>>>(xb, kvwb, k_b, v_b, Vb, knorm);

  wv_field_kernel<<<dim3(4, 512), 256, 0, stream>>>(Vb, knorm, field);
  conv_ema_kernel<<<dim3(4, 16, 8), 256, 0, stream>>>(field, convb);

  // output GEMM with fused bin-duplication (64x64 BK=64, 512 blocks, writes d_out)
  gemm_outc<<<dim3(32, 16), 256, 0, stream>>>(convb, outwb, out_b, (float*)d_out);
}